// Round 4
// baseline (1271.375 us; speedup 1.0000x reference)
//
#include <hip/hip_runtime.h>
#include <cstdint>

#define TOK   8192
#define DIM   1024
#define NE    8
#define HID   4096
#define CAP   8320
#define HROWS 17408
#define MAXRB 136   // max total 128-row blocks across experts

typedef __attribute__((ext_vector_type(4))) float f32x4;
typedef __attribute__((ext_vector_type(8))) short s16x8;

__device__ inline unsigned short f2bf(float f) {
  union { float f; unsigned u; } v; v.f = f;
  unsigned r = v.u + 0x7FFFu + ((v.u >> 16) & 1u);
  return (unsigned short)(r >> 16);
}
__device__ inline float bf2f(unsigned short u) {
  union { unsigned u; float f; } v; v.u = ((unsigned)u) << 16;
  return v.f;
}

// async global->LDS, 16B per lane. LDS dest is wave-uniform base + lane*16.
__device__ __forceinline__ void gload_lds16(const void* gptr, void* lptr) {
  __builtin_amdgcn_global_load_lds(
      (const __attribute__((address_space(1))) unsigned*)gptr,
      (__attribute__((address_space(3))) unsigned*)lptr, 16, 0, 0);
}

// ---------------- transpose+cast W [E][K][N] fp32 -> Wt [E][N][K] bf16 ----------------
__global__ __launch_bounds__(256) void transpose_cast_kernel(const float* __restrict__ W,
                                                             unsigned short* __restrict__ Wt,
                                                             int K, int N) {
  int e = blockIdx.z;
  int n0 = blockIdx.x * 64;
  int k0 = blockIdx.y * 64;
  const float* We = W + (size_t)e * K * N;
  unsigned short* Wte = Wt + (size_t)e * K * N;
  __shared__ float tile[64][65];
  int tid = threadIdx.x;
  int c4 = (tid & 15) * 4;  // 0..60
  int r  = tid >> 4;        // 0..15
#pragma unroll
  for (int rr = 0; rr < 64; rr += 16) {
    f32x4 v = *(const f32x4*)(We + (size_t)(k0 + r + rr) * N + n0 + c4);
    tile[r + rr][c4 + 0] = v[0];
    tile[r + rr][c4 + 1] = v[1];
    tile[r + rr][c4 + 2] = v[2];
    tile[r + rr][c4 + 3] = v[3];
  }
  __syncthreads();
#pragma unroll
  for (int rr = 0; rr < 64; rr += 16) {
    int n = r + rr;
    ushort4 o;
    o.x = f2bf(tile[c4 + 0][n]);
    o.y = f2bf(tile[c4 + 1][n]);
    o.z = f2bf(tile[c4 + 2][n]);
    o.w = f2bf(tile[c4 + 3][n]);
    *(ushort4*)(Wte + (size_t)(n0 + n) * K + k0 + c4) = o;
  }
}

// ---------------- router: one wave per token, fp32 exact; also casts x->bf16 ----------------
__global__ __launch_bounds__(256) void router_kernel(const float* __restrict__ x,
                                                     const float* __restrict__ noise,
                                                     const float* __restrict__ Wg,
                                                     const float* __restrict__ bg,
                                                     const float* __restrict__ Wn,
                                                     const float* __restrict__ bn,
                                                     int* __restrict__ cnt,
                                                     int* __restrict__ tokL,
                                                     float* __restrict__ gateL,
                                                     int* __restrict__ tokmap,
                                                     unsigned short* __restrict__ xb) {
  int t = blockIdx.x * 4 + (threadIdx.x >> 6);
  int lane = threadIdx.x & 63;
  float ag[8] = {0, 0, 0, 0, 0, 0, 0, 0};
  float an[8] = {0, 0, 0, 0, 0, 0, 0, 0};
  const float* xr = x + (size_t)t * DIM;
  unsigned short* xbr = xb + (size_t)t * DIM;
  for (int d0 = lane * 4; d0 < DIM; d0 += 256) {
    f32x4 xv = *(const f32x4*)(xr + d0);
    ushort4 o;
    o.x = f2bf(xv[0]); o.y = f2bf(xv[1]); o.z = f2bf(xv[2]); o.w = f2bf(xv[3]);
    *(ushort4*)(xbr + d0) = o;
#pragma unroll
    for (int q = 0; q < 4; q++) {
      float xq = xv[q];
      const float* wg = Wg + (size_t)(d0 + q) * 8;
      const float* wn = Wn + (size_t)(d0 + q) * 8;
      f32x4 g0 = *(const f32x4*)(wg);
      f32x4 g1 = *(const f32x4*)(wg + 4);
      f32x4 n0 = *(const f32x4*)(wn);
      f32x4 n1 = *(const f32x4*)(wn + 4);
      ag[0] += xq * g0[0]; ag[1] += xq * g0[1]; ag[2] += xq * g0[2]; ag[3] += xq * g0[3];
      ag[4] += xq * g1[0]; ag[5] += xq * g1[1]; ag[6] += xq * g1[2]; ag[7] += xq * g1[3];
      an[0] += xq * n0[0]; an[1] += xq * n0[1]; an[2] += xq * n0[2]; an[3] += xq * n0[3];
      an[4] += xq * n1[0]; an[5] += xq * n1[1]; an[6] += xq * n1[2]; an[7] += xq * n1[3];
    }
  }
#pragma unroll
  for (int off = 32; off >= 1; off >>= 1) {
#pragma unroll
    for (int e = 0; e < 8; e++) {
      ag[e] += __shfl_xor(ag[e], off);
      an[e] += __shfl_xor(an[e], off);
    }
  }
  if (lane == 0) {
    float v[8];
#pragma unroll
    for (int e = 0; e < 8; e++) {
      float lg = ag[e] + bg[e];
      float ln = an[e] + bn[e];
      float sp = (ln > 20.f) ? ln : log1pf(expf(ln));  // stable softplus
      v[e] = lg + noise[(size_t)t * 8 + e] * sp;
    }
    int i1 = 0; float m1 = v[0];
#pragma unroll
    for (int e = 1; e < 8; e++) { if (v[e] > m1) { m1 = v[e]; i1 = e; } }
    int i2 = -1; float m2 = -1e30f;
#pragma unroll
    for (int e = 0; e < 8; e++) { if (e != i1 && v[e] > m2) { m2 = v[e]; i2 = e; } }
    float e2 = expf(m2 - m1);
    float denom = 1.f + e2;
    float g1 = 1.f / denom;
    float g2 = e2 / denom;
    int p1 = atomicAdd(&cnt[i1], 1);
    tokL[i1 * CAP + p1] = t; gateL[i1 * CAP + p1] = g1;
    int p2 = atomicAdd(&cnt[i2], 1);
    tokL[i2 * CAP + p2] = t; gateL[i2 * CAP + p2] = g2;
    tokmap[t * 2 + 0] = (i1 << 20) | p1;
    tokmap[t * 2 + 1] = (i2 << 20) | p2;
  }
}

// ---------------- pad lists to 128-multiples; prefix sums; publish work-list meta ----------------
__global__ __launch_bounds__(256) void pad_kernel(const int* __restrict__ cnt,
                                                  int* __restrict__ hoff,
                                                  int* __restrict__ tokL,
                                                  float* __restrict__ gateL,
                                                  int* __restrict__ meta) {
  __shared__ int cp_s[8];
  if (threadIdx.x == 0) {
    int off = 0, rbsum = 0;
    for (int e = 0; e < 8; e++) {
      int c = cnt[e];
      int cp = (c + 127) & ~127;
      cp_s[e] = cp;
      hoff[e] = off;
      off += cp;
      meta[e] = rbsum;       // rboff[e]
      rbsum += cp >> 7;
    }
    meta[8] = rbsum;         // rboff[8]
    meta[9] = rbsum;         // nrb_tot
  }
  __syncthreads();
  for (int e = 0; e < 8; e++) {
    int c = cnt[e], cp = cp_s[e];
    for (int i = c + threadIdx.x; i < cp; i += 256) {
      tokL[e * CAP + i] = 0;
      gateL[e * CAP + i] = 0.f;
    }
  }
}

// ---------------- phase-pipelined GEMM (T2 swizzle + T3/T4 counted drain + T5 setprio)
// BM=128, BN=256, BK=64. 512 threads = 8 waves (2M x 4N), 64x64 output per wave.
// Double-buffered LDS (96 KB). Per K-tile: 4 phases (one B-quadrant j each, 8 MFMA);
// next tile's 6 global_load_lds issued in phases 0-1; single vmcnt(0) at next tile's
// entry barrier (loads get ~4 MFMA phases to land -> no per-step drain stall).
// T2: slot ^= row&7 on 16B slots, applied on BOTH global source and ds_read (rule 21).
template <int KD, int ND, int NBT, bool GATHER, bool RELU>
__global__ __launch_bounds__(512) void gemm_pipe_kernel(
    const unsigned short* __restrict__ A,    // xb (gather) or h (dense)
    const unsigned short* __restrict__ Bt,   // [E][ND][KD] bf16
    const float* __restrict__ bias,          // [E][ND]
    const int* __restrict__ tokL,
    const int* __restrict__ meta,
    const int* __restrict__ hoff,
    unsigned short* __restrict__ outp) {     // rows x ND bf16
  // ---- compacted work decode, XCD-chunked, remainder-safe bijection (m204) ----
  const int nrbtot = meta[9];
  const int ntot = nrbtot * NBT;
  const int b = blockIdx.x;
  const int c8 = b & 7, ib = b >> 3;
  const int q = ntot >> 3, r8 = ntot & 7;
  if (ib >= q + (c8 < r8 ? 1 : 0)) return;
  const int wid = c8 * q + (c8 < r8 ? c8 : r8) + ib;
  const int nb = wid / nrbtot;
  const int rem = wid - nb * nrbtot;
  int e = 0;
#pragma unroll
  for (int k = 1; k < 8; k++) e += (rem >= meta[k]);
  const int rb = rem - meta[e];
  const int row0 = hoff[e] + rb * 128;
  const int n0 = nb * 256;

  __shared__ unsigned short As[2 * 128 * 64];  // 32 KB, dbuf
  __shared__ unsigned short Bs[2 * 256 * 64];  // 64 KB, dbuf
  __shared__ int toks[128];

  const int tid = threadIdx.x;
  if (GATHER) {
    if (tid < 128) toks[tid] = tokL[e * CAP + rb * 128 + tid];
    __syncthreads();
  }

  const int w = tid >> 6;          // wave 0..7
  const int lane = tid & 63;
  const int srow = tid >> 3;       // staging row-within-64 (0..63)
  const int sg = (tid & 7) ^ (srow & 7);  // pre-swizzled source slot (involution)

  // per-lane global source pointers (swizzled slot), advance 64 elems per K-tile
  const unsigned short* gA0;
  const unsigned short* gA1;
  if (GATHER) {
    gA0 = A + (size_t)toks[srow] * KD + sg * 8;
    gA1 = A + (size_t)toks[64 + srow] * KD + sg * 8;
  } else {
    gA0 = A + (size_t)(row0 + srow) * KD + sg * 8;
    gA1 = A + (size_t)(row0 + 64 + srow) * KD + sg * 8;
  }
  const unsigned short* ebp = Bt + (size_t)e * ND * KD;
  const unsigned short* gB0 = ebp + (size_t)(n0 +       srow) * KD + sg * 8;
  const unsigned short* gB1 = ebp + (size_t)(n0 +  64 + srow) * KD + sg * 8;
  const unsigned short* gB2 = ebp + (size_t)(n0 + 128 + srow) * KD + sg * 8;
  const unsigned short* gB3 = ebp + (size_t)(n0 + 192 + srow) * KD + sg * 8;

  const int wm64 = (w >> 2) * 64;  // 0 or 64
  const int wn   = (w & 3) * 64;   // 0,64,128,192
  const int fr = lane & 15;
  const int fq = lane >> 4;        // 0..3

  f32x4 acc[4][4];
#pragma unroll
  for (int i = 0; i < 4; i++)
#pragma unroll
    for (int j = 0; j < 4; j++) acc[i][j] = (f32x4){0.f, 0.f, 0.f, 0.f};

  const int NT = KD / 64;

  // prologue: stage tile 0 into buf 0
  {
    unsigned short* a = As + w * 512;
    unsigned short* bb = Bs + w * 512;
    gload_lds16(gA0, a);
    gload_lds16(gA1, a + 4096);
    gload_lds16(gB0, bb);
    gload_lds16(gB1, bb + 4096);
    gload_lds16(gB2, bb + 8192);
    gload_lds16(gB3, bb + 12288);
    gA0 += 64; gA1 += 64; gB0 += 64; gB1 += 64; gB2 += 64; gB3 += 64;
  }

  for (int t = 0; t < NT; ++t) {
    const int cur = t & 1, nxt = cur ^ 1;
    const bool pf = (t + 1) < NT;
    // tile-entry: drain this tile's staged loads, then sync (vmcnt+barrier compose
    // per-wave counts into a collective guarantee)
    asm volatile("s_waitcnt vmcnt(0)" ::: "memory");
    __builtin_amdgcn_s_barrier();

    const unsigned short* Ac = As + cur * 8192;
    const unsigned short* Bc = Bs + cur * 16384;

    // ---- phase 0: stage next A + B01; read all A-frags + B(j=0); MFMA ----
    if (pf) {
      unsigned short* a = As + nxt * 8192 + w * 512;
      unsigned short* bb = Bs + nxt * 16384 + w * 512;
      gload_lds16(gA0, a);
      gload_lds16(gA1, a + 4096);
      gload_lds16(gB0, bb);
      gload_lds16(gB1, bb + 4096);
    }
    s16x8 af[4][2];
#pragma unroll
    for (int i = 0; i < 4; i++)
#pragma unroll
      for (int ks = 0; ks < 2; ks++) {
        int row = wm64 + i * 16 + fr;
        af[i][ks] = *(const s16x8*)(Ac + row * 64 + ((ks * 4 + fq) ^ (row & 7)) * 8);
      }
    {
      int brow = wn + 0 * 16 + fr;
      s16x8 bf0 = *(const s16x8*)(Bc + brow * 64 + ((0 * 4 + fq) ^ (brow & 7)) * 8);
      s16x8 bf1 = *(const s16x8*)(Bc + brow * 64 + ((1 * 4 + fq) ^ (brow & 7)) * 8);
      __builtin_amdgcn_s_setprio(1);
#pragma unroll
      for (int i = 0; i < 4; i++) {
        acc[i][0] = __builtin_amdgcn_mfma_f32_16x16x32_bf16(af[i][0], bf0, acc[i][0], 0, 0, 0);
        acc[i][0] = __builtin_amdgcn_mfma_f32_16x16x32_bf16(af[i][1], bf1, acc[i][0], 0, 0, 0);
      }
      __builtin_amdgcn_s_setprio(0);
    }
    __builtin_amdgcn_s_barrier();

    // ---- phase 1: stage next B23; B(j=1); MFMA ----
    if (pf) {
      unsigned short* bb = Bs + nxt * 16384 + w * 512;
      gload_lds16(gB2, bb + 8192);
      gload_lds16(gB3, bb + 12288);
    }
    {
      int brow = wn + 1 * 16 + fr;
      s16x8 bf0 = *(const s16x8*)(Bc + brow * 64 + ((0 * 4 + fq) ^ (brow & 7)) * 8);
      s16x8 bf1 = *(const s16x8*)(Bc + brow * 64 + ((1 * 4 + fq) ^ (brow & 7)) * 8);
      __builtin_amdgcn_s_setprio(1);
#pragma unroll
      for (int i = 0; i < 4; i++) {
        acc[i][1] = __builtin_amdgcn_mfma_f32_16x16x32_bf16(af[i][0], bf0, acc[i][1], 0, 0, 0);
        acc[i][1] = __builtin_amdgcn_mfma_f32_16x16x32_bf16(af[i][1], bf1, acc[i][1], 0, 0, 0);
      }
      __builtin_amdgcn_s_setprio(0);
    }
    __builtin_amdgcn_s_barrier();

    // ---- phase 2: B(j=2); MFMA ----
    {
      int brow = wn + 2 * 16 + fr;
      s16x8 bf0 = *(const s16x8*)(Bc + brow * 64 + ((0 * 4 + fq) ^ (brow & 7)) * 8);
      s16x8 bf1 = *(const s16x8*)(Bc + brow * 64 + ((1 * 4 + fq) ^ (brow & 7)) * 8);
      __builtin_amdgcn_s_setprio(1);
#pragma unroll
      for (int i = 0; i < 4; i++) {
        acc[i][2] = __builtin_amdgcn_mfma_f32_16x16x32_bf16(af[i][0], bf0, acc[i][2], 0, 0, 0);
        acc[i][2] = __builtin_amdgcn_mfma_f32_16x16x32_bf16(af[i][1], bf1, acc[i][2], 0, 0, 0);
      }
      __builtin_amdgcn_s_setprio(0);
    }
    __builtin_amdgcn_s_barrier();

    // ---- phase 3: B(j=3); MFMA (next tile's entry barrier closes the phase) ----
    {
      int brow = wn + 3 * 16 + fr;
      s16x8 bf0 = *(const s16x8*)(Bc + brow * 64 + ((0 * 4 + fq) ^ (brow & 7)) * 8);
      s16x8 bf1 = *(const s16x8*)(Bc + brow * 64 + ((1 * 4 + fq) ^ (brow & 7)) * 8);
      __builtin_amdgcn_s_setprio(1);
#pragma unroll
      for (int i = 0; i < 4; i++) {
        acc[i][3] = __builtin_amdgcn_mfma_f32_16x16x32_bf16(af[i][0], bf0, acc[i][3], 0, 0, 0);
        acc[i][3] = __builtin_amdgcn_mfma_f32_16x16x32_bf16(af[i][1], bf1, acc[i][3], 0, 0, 0);
      }
      __builtin_amdgcn_s_setprio(0);
    }
    gA0 += 64; gA1 += 64; gB0 += 64; gB1 += 64; gB2 += 64; gB3 += 64;
  }

  // ---- epilogue ----
  const float* bp = bias + (size_t)e * ND + n0 + wn;
#pragma unroll
  for (int j = 0; j < 4; j++) {
    float bb = bp[j * 16 + fr];
#pragma unroll
    for (int i = 0; i < 4; i++)
#pragma unroll
      for (int v = 0; v < 4; v++) {
        float val = acc[i][j][v] + bb;
        if (RELU) val = fmaxf(val, 0.f);
        int m = wm64 + i * 16 + fq * 4 + v;
        outp[(size_t)(row0 + m) * ND + n0 + wn + j * 16 + fr] = f2bf(val);
      }
  }
}

// ---------------- combine: out[t] = g1*ybuf[row1] + g2*ybuf[row2] (dense, coalesced)
__global__ __launch_bounds__(256) void combine_kernel(const unsigned short* __restrict__ ybuf,
                                                      const int* __restrict__ tokmap,
                                                      const float* __restrict__ gateL,
                                                      const int* __restrict__ hoff,
                                                      float* __restrict__ out) {
  const int t = blockIdx.x;
  const int m1 = tokmap[t * 2 + 0];
  const int m2 = tokmap[t * 2 + 1];
  const int e1 = m1 >> 20, p1 = m1 & 0xFFFFF;
  const int e2 = m2 >> 20, p2 = m2 & 0xFFFFF;
  const float g1 = gateL[e1 * CAP + p1];
  const float g2 = gateL[e2 * CAP + p2];
  const size_t r1 = (size_t)(hoff[e1] + p1) * DIM;
  const size_t r2 = (size_t)(hoff[e2] + p2) * DIM;
  const int d = threadIdx.x * 4;
  ushort4 u1 = *(const ushort4*)(ybuf + r1 + d);
  ushort4 u2 = *(const ushort4*)(ybuf + r2 + d);
  f32x4 o;
  o[0] = g1 * bf2f(u1.x) + g2 * bf2f(u2.x);
  o[1] = g1 * bf2f(u1.y) + g2 * bf2f(u2.y);
  o[2] = g1 * bf2f(u1.z) + g2 * bf2f(u2.z);
  o[3] = g1 * bf2f(u1.w) + g2 * bf2f(u2.w);
  *(f32x4*)(out + (size_t)t * DIM + d) = o;
}

extern "C" void kernel_launch(void* const* d_in, const int* in_sizes, int n_in,
                              void* d_out, int out_size, void* d_ws, size_t ws_size,
                              hipStream_t stream) {
  const float* x     = (const float*)d_in[0];
  const float* noise = (const float*)d_in[1];
  const float* Wg    = (const float*)d_in[2];
  const float* bg    = (const float*)d_in[3];
  const float* Wn    = (const float*)d_in[4];
  const float* bn    = (const float*)d_in[5];
  const float* W1    = (const float*)d_in[6];
  const float* b1    = (const float*)d_in[7];
  const float* W2    = (const float*)d_in[8];
  const float* b2    = (const float*)d_in[9];
  float* out = (float*)d_out;

  char* ws = (char*)d_ws;
  int*            cnt    = (int*)(ws + 0);
  int*            hoff   = (int*)(ws + 32);
  int*            meta   = (int*)(ws + 64);    // rboff[0..8] + nrb_tot
  int*            tokL   = (int*)(ws + 256);
  float*          gateL  = (float*)(ws + 266496);
  unsigned short* xb     = (unsigned short*)(ws + 532736);
  unsigned short* w1t    = (unsigned short*)(ws + 17309952);   // dead after gemm1
  unsigned short* w2t    = (unsigned short*)(ws + 84418816);
  unsigned short* hbuf   = (unsigned short*)(ws + 151527680);
  int*            tokmap = (int*)(ws + 294134016);
  // ybuf reuses the w1t region (w1t is 67 MB, ybuf needs 35.7 MB; gemm1 finishes
  // reading w1t before gemm2 writes ybuf — same-stream ordering guarantees it).
  unsigned short* ybuf   = w1t;
  // total ws need: 294,199,552 bytes

  hipMemsetAsync(cnt, 0, 64, stream);

  transpose_cast_kernel<<<dim3(HID / 64, DIM / 64, NE), 256, 0, stream>>>(W1, w1t, DIM, HID);
  transpose_cast_kernel<<<dim3(DIM / 64, HID / 64, NE), 256, 0, stream>>>(W2, w2t, HID, DIM);
  router_kernel<<<TOK / 4, 256, 0, stream>>>(x, noise, Wg, bg, Wn, bn, cnt, tokL, gateL, tokmap, xb);
  pad_kernel<<<1, 256, 0, stream>>>(cnt, hoff, tokL, gateL, meta);
  // gemm1: KD=1024, ND=4096, 16 n-blocks of 256
  gemm_pipe_kernel<DIM, HID, 16, true, true>
      <<<MAXRB * 16, 512, 0, stream>>>(xb, w1t, b1, tokL, meta, hoff, hbuf);
  // gemm2: KD=4096, ND=1024, 4 n-blocks of 256
  gemm_pipe_kernel<HID, DIM, 4, false, false>
      <<<MAXRB * 4, 512, 0, stream>>>(hbuf, w2t, b2, tokL, meta, hoff, ybuf);
  combine_kernel<<<TOK, 256, 0, stream>>>(ybuf, tokmap, gateL, hoff, out);
}

// Round 5
// 1048.630 us; speedup vs baseline: 1.2124x; 1.2124x over previous
//
#include <hip/hip_runtime.h>
#include <cstdint>

#define TOK   8192
#define DIM   1024
#define NE    8
#define HID   4096
#define CAP   8320
#define HROWS 17408
#define MAXRB 136   // max total 128-row blocks across experts

typedef __attribute__((ext_vector_type(4))) float f32x4;
typedef __attribute__((ext_vector_type(8))) short s16x8;

__device__ inline unsigned short f2bf(float f) {
  union { float f; unsigned u; } v; v.f = f;
  unsigned r = v.u + 0x7FFFu + ((v.u >> 16) & 1u);
  return (unsigned short)(r >> 16);
}
__device__ inline float bf2f(unsigned short u) {
  union { unsigned u; float f; } v; v.u = ((unsigned)u) << 16;
  return v.f;
}

// async global->LDS, 16B per lane. LDS dest is wave-uniform base + lane*16.
__device__ __forceinline__ void gload_lds16(const void* gptr, void* lptr) {
  __builtin_amdgcn_global_load_lds(
      (const __attribute__((address_space(1))) unsigned*)gptr,
      (__attribute__((address_space(3))) unsigned*)lptr, 16, 0, 0);
}

// ---------------- transpose+cast W [E][K][N] fp32 -> Wt [E][N][K] bf16 ----------------
__global__ __launch_bounds__(256) void transpose_cast_kernel(const float* __restrict__ W,
                                                             unsigned short* __restrict__ Wt,
                                                             int K, int N) {
  int e = blockIdx.z;
  int n0 = blockIdx.x * 64;
  int k0 = blockIdx.y * 64;
  const float* We = W + (size_t)e * K * N;
  unsigned short* Wte = Wt + (size_t)e * K * N;
  __shared__ float tile[64][65];
  int tid = threadIdx.x;
  int c4 = (tid & 15) * 4;  // 0..60
  int r  = tid >> 4;        // 0..15
#pragma unroll
  for (int rr = 0; rr < 64; rr += 16) {
    f32x4 v = *(const f32x4*)(We + (size_t)(k0 + r + rr) * N + n0 + c4);
    tile[r + rr][c4 + 0] = v[0];
    tile[r + rr][c4 + 1] = v[1];
    tile[r + rr][c4 + 2] = v[2];
    tile[r + rr][c4 + 3] = v[3];
  }
  __syncthreads();
#pragma unroll
  for (int rr = 0; rr < 64; rr += 16) {
    int n = r + rr;
    ushort4 o;
    o.x = f2bf(tile[c4 + 0][n]);
    o.y = f2bf(tile[c4 + 1][n]);
    o.z = f2bf(tile[c4 + 2][n]);
    o.w = f2bf(tile[c4 + 3][n]);
    *(ushort4*)(Wte + (size_t)(n0 + n) * K + k0 + c4) = o;
  }
}

// ---------------- router: one wave per token, fp32 exact; also casts x->bf16 ----------------
__global__ __launch_bounds__(256) void router_kernel(const float* __restrict__ x,
                                                     const float* __restrict__ noise,
                                                     const float* __restrict__ Wg,
                                                     const float* __restrict__ bg,
                                                     const float* __restrict__ Wn,
                                                     const float* __restrict__ bn,
                                                     int* __restrict__ cnt,
                                                     int* __restrict__ tokL,
                                                     float* __restrict__ gateL,
                                                     int* __restrict__ tokmap,
                                                     unsigned short* __restrict__ xb) {
  int t = blockIdx.x * 4 + (threadIdx.x >> 6);
  int lane = threadIdx.x & 63;
  float ag[8] = {0, 0, 0, 0, 0, 0, 0, 0};
  float an[8] = {0, 0, 0, 0, 0, 0, 0, 0};
  const float* xr = x + (size_t)t * DIM;
  unsigned short* xbr = xb + (size_t)t * DIM;
  for (int d0 = lane * 4; d0 < DIM; d0 += 256) {
    f32x4 xv = *(const f32x4*)(xr + d0);
    ushort4 o;
    o.x = f2bf(xv[0]); o.y = f2bf(xv[1]); o.z = f2bf(xv[2]); o.w = f2bf(xv[3]);
    *(ushort4*)(xbr + d0) = o;
#pragma unroll
    for (int q = 0; q < 4; q++) {
      float xq = xv[q];
      const float* wg = Wg + (size_t)(d0 + q) * 8;
      const float* wn = Wn + (size_t)(d0 + q) * 8;
      f32x4 g0 = *(const f32x4*)(wg);
      f32x4 g1 = *(const f32x4*)(wg + 4);
      f32x4 n0 = *(const f32x4*)(wn);
      f32x4 n1 = *(const f32x4*)(wn + 4);
      ag[0] += xq * g0[0]; ag[1] += xq * g0[1]; ag[2] += xq * g0[2]; ag[3] += xq * g0[3];
      ag[4] += xq * g1[0]; ag[5] += xq * g1[1]; ag[6] += xq * g1[2]; ag[7] += xq * g1[3];
      an[0] += xq * n0[0]; an[1] += xq * n0[1]; an[2] += xq * n0[2]; an[3] += xq * n0[3];
      an[4] += xq * n1[0]; an[5] += xq * n1[1]; an[6] += xq * n1[2]; an[7] += xq * n1[3];
    }
  }
#pragma unroll
  for (int off = 32; off >= 1; off >>= 1) {
#pragma unroll
    for (int e = 0; e < 8; e++) {
      ag[e] += __shfl_xor(ag[e], off);
      an[e] += __shfl_xor(an[e], off);
    }
  }
  if (lane == 0) {
    float v[8];
#pragma unroll
    for (int e = 0; e < 8; e++) {
      float lg = ag[e] + bg[e];
      float ln = an[e] + bn[e];
      float sp = (ln > 20.f) ? ln : log1pf(expf(ln));  // stable softplus
      v[e] = lg + noise[(size_t)t * 8 + e] * sp;
    }
    int i1 = 0; float m1 = v[0];
#pragma unroll
    for (int e = 1; e < 8; e++) { if (v[e] > m1) { m1 = v[e]; i1 = e; } }
    int i2 = -1; float m2 = -1e30f;
#pragma unroll
    for (int e = 0; e < 8; e++) { if (e != i1 && v[e] > m2) { m2 = v[e]; i2 = e; } }
    float e2 = expf(m2 - m1);
    float denom = 1.f + e2;
    float g1 = 1.f / denom;
    float g2 = e2 / denom;
    int p1 = atomicAdd(&cnt[i1], 1);
    tokL[i1 * CAP + p1] = t; gateL[i1 * CAP + p1] = g1;
    int p2 = atomicAdd(&cnt[i2], 1);
    tokL[i2 * CAP + p2] = t; gateL[i2 * CAP + p2] = g2;
    tokmap[t * 2 + 0] = (i1 << 20) | p1;
    tokmap[t * 2 + 1] = (i2 << 20) | p2;
  }
}

// ---------------- pad lists to 128-multiples; prefix sums; publish work-list meta ----------------
__global__ __launch_bounds__(256) void pad_kernel(const int* __restrict__ cnt,
                                                  int* __restrict__ hoff,
                                                  int* __restrict__ tokL,
                                                  float* __restrict__ gateL,
                                                  int* __restrict__ meta) {
  __shared__ int cp_s[8];
  if (threadIdx.x == 0) {
    int off = 0, rbsum = 0;
    for (int e = 0; e < 8; e++) {
      int c = cnt[e];
      int cp = (c + 127) & ~127;
      cp_s[e] = cp;
      hoff[e] = off;
      off += cp;
      meta[e] = rbsum;       // rboff[e]
      rbsum += cp >> 7;
    }
    meta[8] = rbsum;         // rboff[8]
    meta[9] = rbsum;         // nrb_tot
  }
  __syncthreads();
  for (int e = 0; e < 8; e++) {
    int c = cnt[e], cp = cp_s[e];
    for (int i = c + threadIdx.x; i < cp; i += 256) {
      tokL[e * CAP + i] = 0;
      gateL[e * CAP + i] = 0.f;
    }
  }
}

// ---------------- 3-stage pipelined GEMM (T2 swizzle + T4 counted vmcnt + T5 setprio)
// BM=128, BN=256, BK=64. 512 threads = 8 waves (2M x 4N), 64x64 output per wave.
// LDS: 3 rotating buffers (144 KB). Prologue stages tiles 0,1; tile t issues tile
// t+2's 6 loads right after its entry {vmcnt(6); s_barrier}. vmcnt(6) waits only the
// OLDEST 6 loads (tile t's, issued ~2 tiles ago -> HBM latency covered); newer loads
// stay in flight (T4, never drain to 0 in the loop; peeled last tile drains).
// No intra-tile barriers: 3 buffers remove the intra-tile hazard; compiler
// interleaves the 16 ds_read_b128 with the 32-MFMA cluster via fine lgkmcnt.
// T2: slot ^= row&7 on 16B slots, applied on BOTH global source and ds_read.
template <int KD, int ND, int NBT, bool GATHER, bool RELU>
__global__ __launch_bounds__(512) void gemm_pipe_kernel(
    const unsigned short* __restrict__ A,    // xb (gather) or h (dense)
    const unsigned short* __restrict__ Bt,   // [E][ND][KD] bf16
    const float* __restrict__ bias,          // [E][ND]
    const int* __restrict__ tokL,
    const int* __restrict__ meta,
    const int* __restrict__ hoff,
    unsigned short* __restrict__ outp) {     // rows x ND bf16
  // ---- compacted work decode, XCD-chunked, remainder-safe bijection (m204) ----
  const int nrbtot = meta[9];
  const int ntot = nrbtot * NBT;
  const int b = blockIdx.x;
  const int c8 = b & 7, ib = b >> 3;
  const int q = ntot >> 3, r8 = ntot & 7;
  if (ib >= q + (c8 < r8 ? 1 : 0)) return;
  const int wid = c8 * q + (c8 < r8 ? c8 : r8) + ib;
  const int nb = wid / nrbtot;
  const int rem = wid - nb * nrbtot;
  int e = 0;
#pragma unroll
  for (int k = 1; k < 8; k++) e += (rem >= meta[k]);
  const int rb = rem - meta[e];
  const int row0 = hoff[e] + rb * 128;
  const int n0 = nb * 256;

  __shared__ unsigned short As[3 * 128 * 64];  // 48 KB, 3-stage
  __shared__ unsigned short Bs[3 * 256 * 64];  // 96 KB, 3-stage
  __shared__ int toks[128];

  const int tid = threadIdx.x;
  if (GATHER) {
    if (tid < 128) toks[tid] = tokL[e * CAP + rb * 128 + tid];
    __syncthreads();
  }

  const int w = tid >> 6;          // wave 0..7
  const int lane = tid & 63;
  const int srow = tid >> 3;       // staging row-within-64 (0..63)
  const int sg = (tid & 7) ^ (srow & 7);  // pre-swizzled source slot (involution)

  // per-lane global source pointers (swizzled slot), advance 64 elems per K-tile
  const unsigned short* gA0;
  const unsigned short* gA1;
  if (GATHER) {
    gA0 = A + (size_t)toks[srow] * KD + sg * 8;
    gA1 = A + (size_t)toks[64 + srow] * KD + sg * 8;
  } else {
    gA0 = A + (size_t)(row0 + srow) * KD + sg * 8;
    gA1 = A + (size_t)(row0 + 64 + srow) * KD + sg * 8;
  }
  const unsigned short* ebp = Bt + (size_t)e * ND * KD;
  const unsigned short* gB0 = ebp + (size_t)(n0 +       srow) * KD + sg * 8;
  const unsigned short* gB1 = ebp + (size_t)(n0 +  64 + srow) * KD + sg * 8;
  const unsigned short* gB2 = ebp + (size_t)(n0 + 128 + srow) * KD + sg * 8;
  const unsigned short* gB3 = ebp + (size_t)(n0 + 192 + srow) * KD + sg * 8;

  const int wm64 = (w >> 2) * 64;  // 0 or 64
  const int wn   = (w & 3) * 64;   // 0,64,128,192
  const int fr = lane & 15;
  const int fq = lane >> 4;        // 0..3

  f32x4 acc[4][4];
#pragma unroll
  for (int i = 0; i < 4; i++)
#pragma unroll
    for (int j = 0; j < 4; j++) acc[i][j] = (f32x4){0.f, 0.f, 0.f, 0.f};

  // stage one K-tile into buffer `buf` (6 gload_lds/thread), advance gptrs
  auto stage = [&](int buf) {
    unsigned short* a  = As + buf * 8192  + w * 512;   // shorts: w*1024 bytes
    unsigned short* bb = Bs + buf * 16384 + w * 512;
    gload_lds16(gA0, a);
    gload_lds16(gA1, a + 4096);
    gload_lds16(gB0, bb);
    gload_lds16(gB1, bb + 4096);
    gload_lds16(gB2, bb + 8192);
    gload_lds16(gB3, bb + 12288);
    gA0 += 64; gA1 += 64; gB0 += 64; gB1 += 64; gB2 += 64; gB3 += 64;
  };

#define GEMM_BODY(ACP, BCP)                                                          \
  {                                                                                  \
    s16x8 af[4][2], bf[4][2];                                                        \
    _Pragma("unroll")                                                                \
    for (int i = 0; i < 4; i++)                                                      \
      _Pragma("unroll")                                                              \
      for (int ks = 0; ks < 2; ks++) {                                               \
        int row = wm64 + i * 16 + fr;                                                \
        af[i][ks] = *(const s16x8*)((ACP) + row * 64 + ((ks * 4 + fq) ^ (row & 7)) * 8); \
      }                                                                              \
    _Pragma("unroll")                                                                \
    for (int j = 0; j < 4; j++)                                                      \
      _Pragma("unroll")                                                              \
      for (int ks = 0; ks < 2; ks++) {                                               \
        int row = wn + j * 16 + fr;                                                  \
        bf[j][ks] = *(const s16x8*)((BCP) + row * 64 + ((ks * 4 + fq) ^ (row & 7)) * 8); \
      }                                                                              \
    __builtin_amdgcn_s_setprio(1);                                                   \
    _Pragma("unroll")                                                                \
    for (int j = 0; j < 4; j++)                                                      \
      _Pragma("unroll")                                                              \
      for (int i = 0; i < 4; i++) {                                                  \
        acc[i][j] = __builtin_amdgcn_mfma_f32_16x16x32_bf16(af[i][0], bf[j][0], acc[i][j], 0, 0, 0); \
        acc[i][j] = __builtin_amdgcn_mfma_f32_16x16x32_bf16(af[i][1], bf[j][1], acc[i][j], 0, 0, 0); \
      }                                                                              \
    __builtin_amdgcn_s_setprio(0);                                                   \
  }

  const int NT = KD / 64;
  // prologue: stage tiles 0 and 1
  stage(0);
  stage(1);

  int cur = 0;
  for (int t = 0; t < NT - 1; ++t) {
    // entry: wait only the OLDEST 6 loads (this tile's); keep next tile's in flight
    asm volatile("s_waitcnt vmcnt(6)" ::: "memory");
    __builtin_amdgcn_s_barrier();
    // issue tile t+2's loads first (issue-early; lands ~2 tiles later)
    int nxt2 = cur + 2; if (nxt2 >= 3) nxt2 -= 3;
    if (t + 2 < NT) stage(nxt2);
    const unsigned short* Ac = As + cur * 8192;
    const unsigned short* Bc = Bs + cur * 16384;
    GEMM_BODY(Ac, Bc)
    cur = (cur == 2) ? 0 : cur + 1;
  }
  // peeled last tile: drain remaining loads
  {
    asm volatile("s_waitcnt vmcnt(0)" ::: "memory");
    __builtin_amdgcn_s_barrier();
    const unsigned short* Ac = As + cur * 8192;
    const unsigned short* Bc = Bs + cur * 16384;
    GEMM_BODY(Ac, Bc)
  }
#undef GEMM_BODY

  // ---- epilogue ----
  const float* bp = bias + (size_t)e * ND + n0 + wn;
#pragma unroll
  for (int j = 0; j < 4; j++) {
    float bb = bp[j * 16 + fr];
#pragma unroll
    for (int i = 0; i < 4; i++)
#pragma unroll
      for (int v = 0; v < 4; v++) {
        float val = acc[i][j][v] + bb;
        if (RELU) val = fmaxf(val, 0.f);
        int m = wm64 + i * 16 + fq * 4 + v;
        outp[(size_t)(row0 + m) * ND + n0 + wn + j * 16 + fr] = f2bf(val);
      }
  }
}

// ---------------- combine: out[t] = g1*ybuf[row1] + g2*ybuf[row2] (dense, coalesced)
__global__ __launch_bounds__(256) void combine_kernel(const unsigned short* __restrict__ ybuf,
                                                      const int* __restrict__ tokmap,
                                                      const float* __restrict__ gateL,
                                                      const int* __restrict__ hoff,
                                                      float* __restrict__ out) {
  const int t = blockIdx.x;
  const int m1 = tokmap[t * 2 + 0];
  const int m2 = tokmap[t * 2 + 1];
  const int e1 = m1 >> 20, p1 = m1 & 0xFFFFF;
  const int e2 = m2 >> 20, p2 = m2 & 0xFFFFF;
  const float g1 = gateL[e1 * CAP + p1];
  const float g2 = gateL[e2 * CAP + p2];
  const size_t r1 = (size_t)(hoff[e1] + p1) * DIM;
  const size_t r2 = (size_t)(hoff[e2] + p2) * DIM;
  const int d = threadIdx.x * 4;
  ushort4 u1 = *(const ushort4*)(ybuf + r1 + d);
  ushort4 u2 = *(const ushort4*)(ybuf + r2 + d);
  f32x4 o;
  o[0] = g1 * bf2f(u1.x) + g2 * bf2f(u2.x);
  o[1] = g1 * bf2f(u1.y) + g2 * bf2f(u2.y);
  o[2] = g1 * bf2f(u1.z) + g2 * bf2f(u2.z);
  o[3] = g1 * bf2f(u1.w) + g2 * bf2f(u2.w);
  *(f32x4*)(out + (size_t)t * DIM + d) = o;
}

extern "C" void kernel_launch(void* const* d_in, const int* in_sizes, int n_in,
                              void* d_out, int out_size, void* d_ws, size_t ws_size,
                              hipStream_t stream) {
  const float* x     = (const float*)d_in[0];
  const float* noise = (const float*)d_in[1];
  const float* Wg    = (const float*)d_in[2];
  const float* bg    = (const float*)d_in[3];
  const float* Wn    = (const float*)d_in[4];
  const float* bn    = (const float*)d_in[5];
  const float* W1    = (const float*)d_in[6];
  const float* b1    = (const float*)d_in[7];
  const float* W2    = (const float*)d_in[8];
  const float* b2    = (const float*)d_in[9];
  float* out = (float*)d_out;

  char* ws = (char*)d_ws;
  int*            cnt    = (int*)(ws + 0);
  int*            hoff   = (int*)(ws + 32);
  int*            meta   = (int*)(ws + 64);    // rboff[0..8] + nrb_tot
  int*            tokL   = (int*)(ws + 256);
  float*          gateL  = (float*)(ws + 266496);
  unsigned short* xb     = (unsigned short*)(ws + 532736);
  unsigned short* w1t    = (unsigned short*)(ws + 17309952);   // dead after gemm1
  unsigned short* w2t    = (unsigned short*)(ws + 84418816);
  unsigned short* hbuf   = (unsigned short*)(ws + 151527680);
  int*            tokmap = (int*)(ws + 294134016);
  // ybuf reuses the w1t region (w1t is 67 MB, ybuf needs 35.7 MB; gemm1 finishes
  // reading w1t before gemm2 writes ybuf — same-stream ordering guarantees it).
  unsigned short* ybuf   = w1t;
  // total ws need: 294,199,552 bytes

  hipMemsetAsync(cnt, 0, 64, stream);

  transpose_cast_kernel<<<dim3(HID / 64, DIM / 64, NE), 256, 0, stream>>>(W1, w1t, DIM, HID);
  transpose_cast_kernel<<<dim3(DIM / 64, HID / 64, NE), 256, 0, stream>>>(W2, w2t, HID, DIM);
  router_kernel<<<TOK / 4, 256, 0, stream>>>(x, noise, Wg, bg, Wn, bn, cnt, tokL, gateL, tokmap, xb);
  pad_kernel<<<1, 256, 0, stream>>>(cnt, hoff, tokL, gateL, meta);
  // gemm1: KD=1024, ND=4096, 16 n-blocks of 256
  gemm_pipe_kernel<DIM, HID, 16, true, true>
      <<<MAXRB * 16, 512, 0, stream>>>(xb, w1t, b1, tokL, meta, hoff, hbuf);
  // gemm2: KD=4096, ND=1024, 4 n-blocks of 256
  gemm_pipe_kernel<HID, DIM, 4, false, false>
      <<<MAXRB * 4, 512, 0, stream>>>(hbuf, w2t, b2, tokL, meta, hoff, ybuf);
  combine_kernel<<<TOK, 256, 0, stream>>>(ybuf, tokmap, gateL, hoff, out);
}